// Round 8
// baseline (69.735 us; speedup 1.0000x reference)
//
#include <hip/hip_runtime.h>
#include <stdint.h>

typedef __attribute__((ext_vector_type(8))) short bf16x8;
typedef __attribute__((ext_vector_type(4))) float f32x4;

#define NROWS 4096
#define DDIM  1024
#define NKT   32       // K-tiles of BK=32
#define NTILE 1056     // triangle of 128x64 tiles: sum_{i<32}(64-2i)
#define COS_EPS 1e-8f

__device__ __forceinline__ ushort f2bf(float x) {
  union { float f; uint32_t u; } v; v.f = x;
  uint32_t r = (v.u + 0x7FFF + ((v.u >> 16) & 1)) >> 16;  // RNE
  return (ushort)r;
}

// ---------------- prep: sq, 1/norm, bf16 copy ----------------
extern "C" __global__ void __launch_bounds__(256) prep_kernel(
    const float* __restrict__ F, ushort* __restrict__ Fb,
    float* __restrict__ sq, float* __restrict__ rn) {
  const int row  = blockIdx.x * 4 + (threadIdx.x >> 6);
  const int lane = threadIdx.x & 63;
  const float4* src = (const float4*)(F + (size_t)row * DDIM);
  ushort4* dst = (ushort4*)(Fb + (size_t)row * DDIM);
  float s = 0.f;
#pragma unroll
  for (int it = 0; it < 4; ++it) {
    float4 v = src[it * 64 + lane];
    s += v.x * v.x + v.y * v.y + v.z * v.z + v.w * v.w;
    ushort4 b;
    b.x = f2bf(v.x); b.y = f2bf(v.y); b.z = f2bf(v.z); b.w = f2bf(v.w);
    dst[it * 64 + lane] = b;
  }
#pragma unroll
  for (int off = 32; off; off >>= 1) s += __shfl_down(s, off);
  if (lane == 0) {
    sq[row] = s;
    rn[row] = 1.0f / fmaxf(sqrtf(s), COS_EPS);
  }
}

// ---------------- gram: triangle of 128x64 tiles, 1 wave/block -------------
// 1056 blocks (4.1/CU), 64 threads. Wave-private 36KB LDS ring (3 bufs),
// global_load_lds staging 2 tiles ahead, counted vmcnt(12), NO barriers.
// Register fragment double-buffer; 32 MFMA : 12 ds_read_b128 per K-step.
// LDS chunk swizzle: chunk ^= (row>>2)&3 (2 lanes/bank = free).
extern "C" __global__ void __launch_bounds__(64, 1) gram_kernel(
    const ushort* __restrict__ Fb, const float* __restrict__ sq,
    const float* __restrict__ rn, const int* __restrict__ y,
    float* __restrict__ partials) {
  __shared__ __align__(16) ushort As[3][4096];   // 3 x 128x32 bf16 = 24KB
  __shared__ __align__(16) ushort Bs[3][2048];   // 3 x  64x32 bf16 = 12KB

  // XCD-chunked bijection (1056 = 8*132) + staircase decode
  int sid = (int)(blockIdx.x & 7) * 132 + (int)(blockIdx.x >> 3);
  int ti = 0, rem = sid;
  while (rem >= 64 - 2 * ti) { rem -= 64 - 2 * ti; ++ti; }
  const int tj = 2 * ti + rem;     // row panel ti*128 (128 rows), col panel tj*64

  const int lane = threadIdx.x;    // 0..63
  const int fr = lane & 15, fg = lane >> 4;
  const int l2 = lane >> 2;
  // staging source col swizzle: chunk' = (lane&3) ^ ((lane>>4)&3)  (see notes)
  const int gsw = ((lane & 3) ^ ((lane >> 4) & 3)) * 8;

  const ushort* pA[8];
  const ushort* pB[4];
#pragma unroll
  for (int p = 0; p < 8; ++p)
    pA[p] = Fb + (size_t)(ti * 128 + p * 16 + l2) * DDIM + gsw;
#pragma unroll
  for (int p = 0; p < 4; ++p)
    pB[p] = Fb + (size_t)(tj * 64 + p * 16 + l2) * DDIM + gsw;

  f32x4 acc[8][4] = {};
  bf16x8 fa[2][8], fb[2][4];

  // fragment read: row = frag*16+fr, chunk = fg ^ ((fr>>2)&3)
  const int abase = fr * 32 + (fg ^ ((fr >> 2) & 3)) * 8;

#define STAGE(kt) do {                                                      \
    const int _b = (kt) % 3;                                                \
    _Pragma("unroll")                                                       \
    for (int _p = 0; _p < 8; ++_p)                                          \
      __builtin_amdgcn_global_load_lds(                                     \
        (const __attribute__((address_space(1))) uint32_t*)(pA[_p] + (kt) * 32), \
        (__attribute__((address_space(3))) uint32_t*)(&As[_b][_p * 512]),   \
        16, 0, 0);                                                          \
    _Pragma("unroll")                                                       \
    for (int _p = 0; _p < 4; ++_p)                                          \
      __builtin_amdgcn_global_load_lds(                                     \
        (const __attribute__((address_space(1))) uint32_t*)(pB[_p] + (kt) * 32), \
        (__attribute__((address_space(3))) uint32_t*)(&Bs[_b][_p * 512]),   \
        16, 0, 0);                                                          \
  } while (0)

#define LOADFRAGS(set, kt) do {                                             \
    const ushort* _a = &As[(kt) % 3][0] + abase;                            \
    const ushort* _bp = &Bs[(kt) % 3][0] + abase;                           \
    _Pragma("unroll")                                                       \
    for (int _m = 0; _m < 8; ++_m)                                          \
      fa[set][_m] = *(const bf16x8*)(_a + _m * 512);                        \
    _Pragma("unroll")                                                       \
    for (int _n = 0; _n < 4; ++_n)                                          \
      fb[set][_n] = *(const bf16x8*)(_bp + _n * 512);                       \
  } while (0)

#define MFMA32(set) do {                                                    \
    __builtin_amdgcn_s_setprio(1);                                          \
    _Pragma("unroll")                                                       \
    for (int _m = 0; _m < 8; ++_m)                                          \
      _Pragma("unroll")                                                     \
      for (int _n = 0; _n < 4; ++_n)                                        \
        acc[_m][_n] = __builtin_amdgcn_mfma_f32_16x16x32_bf16(              \
            fa[set][_m], fb[set][_n], acc[_m][_n], 0, 0, 0);                \
    __builtin_amdgcn_s_setprio(0);                                          \
  } while (0)

  // prologue: tiles 0,1 in flight (24 loads)
  STAGE(0);
  STAGE(1);

#pragma unroll
  for (int kt = 0; kt < NKT; ++kt) {
    if (kt + 2 < NKT) STAGE(kt + 2);               // 12 loads, 2 ahead
    if (kt < NKT - 2)       asm volatile("s_waitcnt vmcnt(12)");
    else if (kt == NKT - 2) asm volatile("s_waitcnt vmcnt(0)");
    __builtin_amdgcn_sched_barrier(0);             // pin ds_reads below wait
    if (kt == 0) LOADFRAGS(0, 0);
    if (kt < NKT - 1) LOADFRAGS((kt + 1) & 1, kt + 1);
    MFMA32(kt & 1);   // compiler emits counted lgkmcnt for prev set's reads
  }

#undef STAGE
#undef LOADFRAGS
#undef MFMA32

  // ---------- epilogue: per-element weight handles diagonal straddle ------
  float sqc[4], rnc[4];
  int   yc[4];
#pragma unroll
  for (int n = 0; n < 4; ++n) {
    const int gj = tj * 64 + n * 16 + fr;
    sqc[n] = sq[gj]; rnc[n] = rn[gj]; yc[n] = y[gj];
  }
  float lsum = 0.f;
#pragma unroll
  for (int m = 0; m < 8; ++m) {
#pragma unroll
    for (int v = 0; v < 4; ++v) {
      const int gi = ti * 128 + m * 16 + fg * 4 + v;
      const float sqi = sq[gi], rni = rn[gi];
      const int yi = y[gi];
#pragma unroll
      for (int n = 0; n < 4; ++n) {
        const int gj = tj * 64 + n * 16 + fr;
        const float g  = acc[m][n][v];
        const float d2 = sqi + sqc[n] - 2.0f * g;
        const float dist = d2 > 0.f ? sqrtf(d2) : 0.f;
        const float sim  = g * rni * rnc[n];
        const float sgn  = (yi == yc[n]) ? 1.0f : -1.0f;
        const float wgt  = (gj > gi) ? 2.0f : ((gj == gi) ? 1.0f : 0.0f);
        lsum += wgt * sgn * (dist - sim);
      }
    }
  }
#pragma unroll
  for (int off = 32; off; off >>= 1) lsum += __shfl_down(lsum, off);
  if (lane == 0) partials[blockIdx.x] = lsum;
}

// ---------------- deterministic final reduce ----------------
extern "C" __global__ void __launch_bounds__(256) reduce_kernel(
    const float* __restrict__ partials, float* __restrict__ out) {
  float s = 0.f;
  for (int i = threadIdx.x; i < NTILE; i += 256) s += partials[i];
#pragma unroll
  for (int off = 32; off; off >>= 1) s += __shfl_down(s, off);
  __shared__ float ws[4];
  if ((threadIdx.x & 63) == 0) ws[threadIdx.x >> 6] = s;
  __syncthreads();
  if (threadIdx.x == 0) out[0] = ws[0] + ws[1] + ws[2] + ws[3];
}

extern "C" void kernel_launch(void* const* d_in, const int* in_sizes, int n_in,
                              void* d_out, int out_size, void* d_ws, size_t ws_size,
                              hipStream_t stream) {
  const float* F = (const float*)d_in[0];
  const int*   y = (const int*)d_in[1];
  float* out = (float*)d_out;

  ushort* Fb = (ushort*)d_ws;                                 // 8 MB bf16
  float*  sq = (float*)((char*)d_ws + (size_t)NROWS * DDIM * 2);
  float*  rn = sq + NROWS;
  float*  partials = rn + NROWS;

  prep_kernel<<<NROWS / 4, 256, 0, stream>>>(F, Fb, sq, rn);
  gram_kernel<<<NTILE, 64, 0, stream>>>(Fb, sq, rn, y, partials);
  reduce_kernel<<<1, 256, 0, stream>>>(partials, out);
}

// Round 9
// 51.454 us; speedup vs baseline: 1.3553x; 1.3553x over previous
//
#include <hip/hip_runtime.h>
#include <stdint.h>

typedef __attribute__((ext_vector_type(8))) short bf16x8;
typedef __attribute__((ext_vector_type(4))) float f32x4;

#define NROWS 4096
#define DDIM  1024
#define NIT   8        // iterations; each covers 2 K-steps of BK=64
#define GBLK  256      // 16x16 grid of 256x256 output tiles (full gram)
#define COS_EPS 1e-8f

__device__ __forceinline__ ushort f2bf(float x) {
  union { float f; uint32_t u; } v; v.f = x;
  uint32_t r = (v.u + 0x7FFF + ((v.u >> 16) & 1)) >> 16;  // RNE
  return (ushort)r;
}

__device__ __forceinline__ void gload16(const ushort* g, ushort* l) {
  __builtin_amdgcn_global_load_lds(
      (const __attribute__((address_space(1))) uint32_t*)g,
      (__attribute__((address_space(3))) uint32_t*)l, 16, 0, 0);
}

// ---------------- prep: sq, 1/norm, bf16 copy ----------------
extern "C" __global__ void __launch_bounds__(256) prep_kernel(
    const float* __restrict__ F, ushort* __restrict__ Fb,
    float* __restrict__ sq, float* __restrict__ rn) {
  const int row  = blockIdx.x * 4 + (threadIdx.x >> 6);
  const int lane = threadIdx.x & 63;
  const float4* src = (const float4*)(F + (size_t)row * DDIM);
  ushort4* dst = (ushort4*)(Fb + (size_t)row * DDIM);
  float s = 0.f;
#pragma unroll
  for (int it = 0; it < 4; ++it) {
    float4 v = src[it * 64 + lane];
    s += v.x * v.x + v.y * v.y + v.z * v.z + v.w * v.w;
    ushort4 b;
    b.x = f2bf(v.x); b.y = f2bf(v.y); b.z = f2bf(v.z); b.w = f2bf(v.w);
    dst[it * 64 + lane] = b;
  }
#pragma unroll
  for (int off = 32; off; off >>= 1) s += __shfl_down(s, off);
  if (lane == 0) {
    sq[row] = s;
    rn[row] = 1.0f / fmaxf(sqrtf(s), COS_EPS);
  }
}

// ---------------- fused gram: m201-style 256^2 8-phase + loss epilogue -----
// 512 thr = 8 waves (2M x 4N), per-wave 128x64 out. BK=64, 2 K-steps/iter,
// 8 phases/iter: {4-8 ds_read_b128 | 1 half-tile stage (2 gload_lds) |
// bar | 16 MFMA (setprio) | bar}. vmcnt(6) only at phases 4 and 8.
// LDS [2 dbuf][2 half][128x64] per operand = 128 KB. Chunk XOR-swizzle
// c' = c ^ (row&7) applied on BOTH sides (pre-permuted global source +
// swizzled ds_read), LDS written linearly by global_load_lds.
extern "C" __global__ void __launch_bounds__(512, 1) gram_kernel(
    const ushort* __restrict__ Fb, const float* __restrict__ sq,
    const float* __restrict__ rn, const int* __restrict__ y,
    float* __restrict__ partials) {
  __shared__ __align__(16) ushort Al[2][2][8192];  // [dbuf][half][128*64]
  __shared__ __align__(16) ushort Bl[2][2][8192];

  // XCD-aware remap (256 % 8 == 0 -> bijective)
  const int wg = (int)(blockIdx.x & 7) * 32 + (int)(blockIdx.x >> 3);
  const int bi = wg >> 4, bj = wg & 15;

  const int tid  = threadIdx.x;
  const int lane = tid & 63;
  const int wid  = tid >> 6;
  const int wr   = wid >> 2;      // 0..1 : 128-row half (A-half selector)
  const int wc   = wid & 3;       // 0..3 : 64-col group
  const int hB   = wc >> 1;       // B-half selector
  const int bsub = (wc & 1) * 4096;
  const int fr   = lane & 15, fg = lane >> 4;

  // staging: LDS 16B-slot s=(round*512+tid) holds global(row=s>>3, c=c'^(row&7))
  const int srow = tid >> 3;                               // 0..63
  const int sch  = ((tid & 7) ^ ((tid >> 3) & 7)) * 8;     // bf16 units
  const ushort* gA0 = Fb + (size_t)(bi * 256 + srow) * DDIM + sch;
  const ushort* gA1 = gA0 + (size_t)128 * DDIM;
  const ushort* gB0 = Fb + (size_t)(bj * 256 + srow) * DDIM + sch;
  const ushort* gB1 = gB0 + (size_t)128 * DDIM;

  // fragment read offsets (ushort units): row*64 + (c ^ (fr&7))*8, c = kk*4+fg
  const int achk0 = ((fg)     ^ (fr & 7)) * 8;
  const int achk1 = ((4 + fg) ^ (fr & 7)) * 8;
  const int frow  = fr * 64;

  f32x4 acc[2][4][4] = {};
  bf16x8 vb[4];

#define STAGE_A(d2, h, ks) do {                                             \
    const ushort* _s = ((h) ? gA1 : gA0) + (ks) * 64;                       \
    ushort* _d = &Al[d2][h][0] + tid * 8;                                   \
    gload16(_s, _d);                                                        \
    gload16(_s + (size_t)64 * DDIM, _d + 4096);                             \
  } while (0)
#define STAGE_B(d2, h, ks) do {                                             \
    const ushort* _s = ((h) ? gB1 : gB0) + (ks) * 64;                       \
    ushort* _d = &Bl[d2][h][0] + tid * 8;                                   \
    gload16(_s, _d);                                                        \
    gload16(_s + (size_t)64 * DDIM, _d + 4096);                             \
  } while (0)

  // one phase: quadrant (mh, kk); LB=1 loads B[kk] (reused by mh=1 phase)
#define PHASE(d, mh, kk, LB, STMT, VMW) do {                                \
    const ushort* _ab = &Al[d][wr][0] + (mh) * 4096 + frow + achk##kk;      \
    bf16x8 _a0 = *(const bf16x8*)(_ab);                                     \
    bf16x8 _a1 = *(const bf16x8*)(_ab + 1024);                              \
    bf16x8 _a2 = *(const bf16x8*)(_ab + 2048);                              \
    bf16x8 _a3 = *(const bf16x8*)(_ab + 3072);                              \
    if (LB) {                                                               \
      const ushort* _bb = &Bl[d][hB][0] + bsub + frow + achk##kk;           \
      vb[0] = *(const bf16x8*)(_bb);                                        \
      vb[1] = *(const bf16x8*)(_bb + 1024);                                 \
      vb[2] = *(const bf16x8*)(_bb + 2048);                                 \
      vb[3] = *(const bf16x8*)(_bb + 3072);                                 \
    }                                                                       \
    STMT;                                                                   \
    VMW;                                                                    \
    __builtin_amdgcn_s_barrier();                                           \
    __builtin_amdgcn_s_setprio(1);                                          \
    _Pragma("unroll")                                                       \
    for (int _n = 0; _n < 4; ++_n) {                                        \
      acc[mh][0][_n] = __builtin_amdgcn_mfma_f32_16x16x32_bf16(             \
          _a0, vb[_n], acc[mh][0][_n], 0, 0, 0);                            \
      acc[mh][1][_n] = __builtin_amdgcn_mfma_f32_16x16x32_bf16(             \
          _a1, vb[_n], acc[mh][1][_n], 0, 0, 0);                            \
      acc[mh][2][_n] = __builtin_amdgcn_mfma_f32_16x16x32_bf16(             \
          _a2, vb[_n], acc[mh][2][_n], 0, 0, 0);                            \
      acc[mh][3][_n] = __builtin_amdgcn_mfma_f32_16x16x32_bf16(             \
          _a3, vb[_n], acc[mh][3][_n], 0, 0, 0);                            \
    }                                                                       \
    __builtin_amdgcn_s_setprio(0);                                          \
    __builtin_amdgcn_s_barrier();                                           \
  } while (0)

#define VM6 asm volatile("s_waitcnt vmcnt(6)")
#define VM0 asm volatile("s_waitcnt vmcnt(0)")
#define NOP ((void)0)

  // prologue: stage K-steps 0,1 into dbuf0 (16 loads); wait K0 (8 newest out)
  STAGE_A(0, 0, 0); STAGE_B(0, 0, 0); STAGE_A(0, 1, 0); STAGE_B(0, 1, 0);
  STAGE_A(0, 0, 1); STAGE_B(0, 0, 1); STAGE_A(0, 1, 1); STAGE_B(0, 1, 1);
  asm volatile("s_waitcnt vmcnt(8)");
  __builtin_amdgcn_s_barrier();

#pragma unroll 1
  for (int t = 0; t < NIT; ++t) {
    const int d = t & 1, d2 = d ^ 1;
    const int ks0 = 2 * t, ks1 = 2 * t + 1;
    const int ksA = 2 * t + 2, ksB = 2 * t + 3;
    const bool st = (t < NIT - 1);
    // K-step ks0
    PHASE(d, 0, 0, 1, if (st) STAGE_A(d2, 0, ksA), NOP);
    PHASE(d, 1, 0, 0, if (st) STAGE_B(d2, 0, ksA), NOP);
    PHASE(d, 0, 1, 1, if (st) STAGE_A(d2, 1, ksA), NOP);
    PHASE(d, 1, 1, 0, if (st) STAGE_B(d2, 1, ksA), if (st) { VM6; } else { VM0; });
    // K-step ks1
    PHASE(d, 0, 0, 1, if (st) STAGE_A(d2, 0, ksB), NOP);
    PHASE(d, 1, 0, 0, if (st) STAGE_B(d2, 0, ksB), NOP);
    PHASE(d, 0, 1, 1, if (st) STAGE_A(d2, 1, ksB), NOP);
    PHASE(d, 1, 1, 0, if (st) STAGE_B(d2, 1, ksB), if (st) { VM6; });
  }

#undef STAGE_A
#undef STAGE_B
#undef PHASE
#undef VM6
#undef VM0
#undef NOP

  // ---------- epilogue (full gram: every pair once) ----------
  float sqc[4], rnc[4];
  int   yc[4];
#pragma unroll
  for (int n = 0; n < 4; ++n) {
    const int gj = bj * 256 + wc * 64 + n * 16 + fr;
    sqc[n] = sq[gj]; rnc[n] = rn[gj]; yc[n] = y[gj];
  }
  float lsum = 0.f;
#pragma unroll
  for (int mh = 0; mh < 2; ++mh)
#pragma unroll
    for (int mt = 0; mt < 4; ++mt)
#pragma unroll
      for (int v = 0; v < 4; ++v) {
        const int gi = bi * 256 + wr * 128 + mh * 64 + mt * 16 + fg * 4 + v;
        const float sqi = sq[gi], rni = rn[gi];
        const int yi = y[gi];
#pragma unroll
        for (int n = 0; n < 4; ++n) {
          const float g  = acc[mh][mt][n][v];
          const float d2 = sqi + sqc[n] - 2.0f * g;
          const float dist = d2 > 0.f ? sqrtf(d2) : 0.f;
          const float sim  = g * rni * rnc[n];
          lsum += (yi == yc[n]) ? (dist - sim) : (sim - dist);
        }
      }
#pragma unroll
  for (int off = 32; off; off >>= 1) lsum += __shfl_down(lsum, off);
  __shared__ float wsum[8];
  if (lane == 0) wsum[wid] = lsum;
  __syncthreads();
  if (tid == 0) {
    float tsum = 0.f;
#pragma unroll
    for (int i = 0; i < 8; ++i) tsum += wsum[i];
    partials[blockIdx.x] = tsum;
  }
}

// ---------------- deterministic final reduce ----------------
extern "C" __global__ void __launch_bounds__(256) reduce_kernel(
    const float* __restrict__ partials, float* __restrict__ out) {
  float s = 0.f;
  for (int i = threadIdx.x; i < GBLK; i += 256) s += partials[i];
#pragma unroll
  for (int off = 32; off; off >>= 1) s += __shfl_down(s, off);
  __shared__ float ws[4];
  if ((threadIdx.x & 63) == 0) ws[threadIdx.x >> 6] = s;
  __syncthreads();
  if (threadIdx.x == 0) out[0] = ws[0] + ws[1] + ws[2] + ws[3];
}

extern "C" void kernel_launch(void* const* d_in, const int* in_sizes, int n_in,
                              void* d_out, int out_size, void* d_ws, size_t ws_size,
                              hipStream_t stream) {
  const float* F = (const float*)d_in[0];
  const int*   y = (const int*)d_in[1];
  float* out = (float*)d_out;

  ushort* Fb = (ushort*)d_ws;                                 // 8 MB bf16
  float*  sq = (float*)((char*)d_ws + (size_t)NROWS * DDIM * 2);
  float*  rn = sq + NROWS;
  float*  partials = rn + NROWS;

  prep_kernel<<<NROWS / 4, 256, 0, stream>>>(F, Fb, sq, rn);
  gram_kernel<<<GBLK, 512, 0, stream>>>(Fb, sq, rn, y, partials);
  reduce_kernel<<<1, 256, 0, stream>>>(partials, out);
}

// Round 10
// 41.458 us; speedup vs baseline: 1.6821x; 1.2411x over previous
//
#include <hip/hip_runtime.h>
#include <stdint.h>

typedef __attribute__((ext_vector_type(4)))  int   i32x4;
typedef __attribute__((ext_vector_type(8)))  int   i32x8;
typedef __attribute__((ext_vector_type(16))) float f32x16;

#define NROWS 4096
#define DDIM  1024     // bytes per fp8 row (= 1024 elements)
#define NKT   16       // K-tiles of 64 bytes
#define GBLK  256      // 16x16 grid of 256x256 output tiles (full gram)
#define COS_EPS 1e-8f
#define SCL   0x7F7F7F7F   // E8M0 = 127 -> scale 1.0 in every byte

__device__ __forceinline__ void gload16(const uint8_t* g, uint8_t* l) {
  __builtin_amdgcn_global_load_lds(
      (const __attribute__((address_space(1))) uint32_t*)g,
      (__attribute__((address_space(3))) uint32_t*)l, 16, 0, 0);
}

// ---------------- prep: sq, 1/norm, fp8 e4m3 copy ----------------
extern "C" __global__ void __launch_bounds__(256) prep_kernel(
    const float* __restrict__ F, uint8_t* __restrict__ Fb,
    float* __restrict__ sq, float* __restrict__ rn) {
  const int row  = blockIdx.x * 4 + (threadIdx.x >> 6);
  const int lane = threadIdx.x & 63;
  const float4* src = (const float4*)(F + (size_t)row * DDIM + lane * 16);
  float4 v[4];
#pragma unroll
  for (int i = 0; i < 4; ++i) v[i] = src[i];
  float s = 0.f;
#pragma unroll
  for (int i = 0; i < 4; ++i)
    s += v[i].x * v[i].x + v[i].y * v[i].y + v[i].z * v[i].z + v[i].w * v[i].w;
  uint32_t d[4];
#pragma unroll
  for (int i = 0; i < 4; ++i) {
    int w = __builtin_amdgcn_cvt_pk_fp8_f32(v[i].x, v[i].y, 0, false);
    w = __builtin_amdgcn_cvt_pk_fp8_f32(v[i].z, v[i].w, w, true);
    d[i] = (uint32_t)w;
  }
  *(uint4*)(Fb + (size_t)row * DDIM + lane * 16) = make_uint4(d[0], d[1], d[2], d[3]);
#pragma unroll
  for (int off = 32; off; off >>= 1) s += __shfl_down(s, off);
  if (lane == 0) {
    sq[row] = s;
    rn[row] = 1.0f / fmaxf(sqrtf(s), COS_EPS);
  }
}

// ---------------- fused gram: fp8 MX (scale=1) 256^2 + loss epilogue -------
// 8 waves (2M x 4N), per-wave 128x64. mfma_scale_f32_32x32x64_f8f6f4.
// 16 K-tiles of 64 B; 4-slot LDS ring (4 x 32 KB = 128 KB); stage 2 ahead;
// counted vmcnt(4) once per K-tile; 2 phases/K-tile {ds | stage | bar |
// 4 MFMA setprio | bar}. LDS: row-pair layout, u-row = 128 B holds global
// rows (2u,2u+1); granule g = (4h+c)^(u&7) -> 2 lanes/bank-group (free).
// Staged linearly by global_load_lds from pre-permuted global source.
extern "C" __global__ void __launch_bounds__(512, 1) gram_kernel(
    const uint8_t* __restrict__ Fb, const float* __restrict__ sq,
    const float* __restrict__ rn, const int* __restrict__ y,
    float* __restrict__ partials) {
  __shared__ __align__(16) uint8_t As[4][16384];
  __shared__ __align__(16) uint8_t Bs[4][16384];

  // XCD-aware remap (256 % 8 == 0 -> bijective)
  const int wg = (int)(blockIdx.x & 7) * 32 + (int)(blockIdx.x >> 3);
  const int bi = wg >> 4, bj = wg & 15;

  const int tid  = threadIdx.x;
  const int lane = tid & 63;
  const int wid  = tid >> 6;
  const int wr   = wid >> 2;      // 0..1 : 128-row half
  const int wc   = wid & 3;       // 0..3 : 64-col group
  const int kg   = lane >> 5;     // K-half of fragment
  const int r32  = lane & 31;

  // ---- staging source decode (inverse of LDS map) ----
  const int u7 = (tid >> 3) & 7;
  const int hc = (tid & 7) ^ u7;            // (4h + c)
  const int srow = 2 * (tid >> 3) + ((hc >> 2) & 1);   // 0..127
  const int scol = (hc & 3) * 16;
  const uint8_t* gA0 = Fb + (size_t)(bi * 256 + srow) * DDIM + scol;
  const uint8_t* gB0 = Fb + (size_t)(bj * 256 + srow) * DDIM + scol;
  uint8_t* ldsA = &As[0][0] + tid * 16;
  uint8_t* ldsB = &Bs[0][0] + tid * 16;

  // ---- fragment read offsets (within a 16 KB slot) ----
  int offA[4], offB[2];
#pragma unroll
  for (int mt = 0; mt < 4; ++mt) {
    const int R = wr * 128 + mt * 32 + r32;
    const int u = R >> 1, h = R & 1;
    offA[mt] = u * 128 + (((h << 2) + 2 * kg) ^ (u & 7)) * 16;
  }
#pragma unroll
  for (int nb = 0; nb < 2; ++nb) {
    const int R = wc * 64 + nb * 32 + r32;
    const int u = R >> 1, h = R & 1;
    offB[nb] = u * 128 + (((h << 2) + 2 * kg) ^ (u & 7)) * 16;
  }

  f32x16 acc[4][2] = {};

#define STAGE(kt2) do {                                                     \
    const int _sl = (kt2) & 3;                                              \
    gload16(gA0 + (kt2) * 64, ldsA + _sl * 16384);                          \
    gload16(gA0 + (size_t)128 * DDIM + (kt2) * 64, ldsA + _sl * 16384 + 8192); \
    gload16(gB0 + (kt2) * 64, ldsB + _sl * 16384);                          \
    gload16(gB0 + (size_t)128 * DDIM + (kt2) * 64, ldsB + _sl * 16384 + 8192); \
  } while (0)

#define LDF(dst, base, off) do {                                            \
    i32x4 _lo = *(const i32x4*)((base) + (off));                            \
    i32x4 _hi = *(const i32x4*)((base) + ((off) ^ 16));                     \
    dst[0] = _lo[0]; dst[1] = _lo[1]; dst[2] = _lo[2]; dst[3] = _lo[3];     \
    dst[4] = _hi[0]; dst[5] = _hi[1]; dst[6] = _hi[2]; dst[7] = _hi[3];     \
  } while (0)

#define MM(mt, nb, a, b)                                                    \
    acc[mt][nb] = __builtin_amdgcn_mfma_scale_f32_32x32x64_f8f6f4(          \
        a, b, acc[mt][nb], 0, 0, 0, SCL, 0, SCL)

  // prologue: K-tiles 0,1 in flight; wait tile 0 (leave tile 1's 4)
  STAGE(0); STAGE(1);
  asm volatile("s_waitcnt vmcnt(4)");
  __builtin_amdgcn_s_barrier();

#pragma unroll 1
  for (int kt = 0; kt < NKT; ++kt) {
    const uint8_t* sa = &As[0][0] + (kt & 3) * 16384;
    const uint8_t* sb = &Bs[0][0] + (kt & 3) * 16384;
    i32x8 a0, a1, a2, a3, b0, b1;

    // ---- phase 0: B + A(mt0,1) reads | stage A(kt+2) | 4 MFMA ----
    LDF(b0, sb, offB[0]); LDF(b1, sb, offB[1]);
    LDF(a0, sa, offA[0]); LDF(a1, sa, offA[1]);
    if (kt + 2 < NKT) {
      const int _sl = (kt + 2) & 3;
      gload16(gA0 + (kt + 2) * 64, ldsA + _sl * 16384);
      gload16(gA0 + (size_t)128 * DDIM + (kt + 2) * 64, ldsA + _sl * 16384 + 8192);
    }
    __builtin_amdgcn_s_barrier();
    __builtin_amdgcn_s_setprio(1);
    MM(0, 0, a0, b0); MM(0, 1, a0, b1);
    MM(1, 0, a1, b0); MM(1, 1, a1, b1);
    __builtin_amdgcn_s_setprio(0);
    __builtin_amdgcn_s_barrier();

    // ---- phase 1: A(mt2,3) reads | stage B(kt+2) | counted vmcnt | 4 MFMA
    LDF(a2, sa, offA[2]); LDF(a3, sa, offA[3]);
    if (kt + 2 < NKT) {
      const int _sl = (kt + 2) & 3;
      gload16(gB0 + (kt + 2) * 64, ldsB + _sl * 16384);
      gload16(gB0 + (size_t)128 * DDIM + (kt + 2) * 64, ldsB + _sl * 16384 + 8192);
    }
    if (kt < NKT - 2)       asm volatile("s_waitcnt vmcnt(4)");
    else if (kt == NKT - 2) asm volatile("s_waitcnt vmcnt(0)");
    __builtin_amdgcn_s_barrier();
    __builtin_amdgcn_s_setprio(1);
    MM(2, 0, a2, b0); MM(2, 1, a2, b1);
    MM(3, 0, a3, b0); MM(3, 1, a3, b1);
    __builtin_amdgcn_s_setprio(0);
    __builtin_amdgcn_s_barrier();
  }

#undef STAGE
#undef LDF
#undef MM

  // ---------- epilogue: C/D 32x32 layout col=lane&31, row=(e&3)+8*(e>>2)+4*kg
  float sqc[2], rnc[2];
  int   yc[2];
#pragma unroll
  for (int nb = 0; nb < 2; ++nb) {
    const int gj = bj * 256 + wc * 64 + nb * 32 + r32;
    sqc[nb] = sq[gj]; rnc[nb] = rn[gj]; yc[nb] = y[gj];
  }
  float lsum = 0.f;
#pragma unroll
  for (int mt = 0; mt < 4; ++mt) {
#pragma unroll
    for (int e = 0; e < 16; ++e) {
      const int gi = bi * 256 + wr * 128 + mt * 32 + (e & 3) + 8 * (e >> 2) + 4 * kg;
      const float sqi = sq[gi], rni = rn[gi];
      const int yi = y[gi];
#pragma unroll
      for (int nb = 0; nb < 2; ++nb) {
        const float g  = acc[mt][nb][e];
        const float d2 = sqi + sqc[nb] - 2.0f * g;
        const float dist = d2 > 0.f ? sqrtf(d2) : 0.f;
        const float sim  = g * rni * rnc[nb];
        lsum += (yi == yc[nb]) ? (dist - sim) : (sim - dist);
      }
    }
  }
#pragma unroll
  for (int off = 32; off; off >>= 1) lsum += __shfl_down(lsum, off);
  __shared__ float wsum[8];
  if (lane == 0) wsum[wid] = lsum;
  __syncthreads();
  if (tid == 0) {
    float t = 0.f;
#pragma unroll
    for (int i = 0; i < 8; ++i) t += wsum[i];
    partials[blockIdx.x] = t;
  }
}

// ---------------- deterministic final reduce ----------------
extern "C" __global__ void __launch_bounds__(256) reduce_kernel(
    const float* __restrict__ partials, float* __restrict__ out) {
  float s = 0.f;
  for (int i = threadIdx.x; i < GBLK; i += 256) s += partials[i];
#pragma unroll
  for (int off = 32; off; off >>= 1) s += __shfl_down(s, off);
  __shared__ float ws[4];
  if ((threadIdx.x & 63) == 0) ws[threadIdx.x >> 6] = s;
  __syncthreads();
  if (threadIdx.x == 0) out[0] = ws[0] + ws[1] + ws[2] + ws[3];
}

extern "C" void kernel_launch(void* const* d_in, const int* in_sizes, int n_in,
                              void* d_out, int out_size, void* d_ws, size_t ws_size,
                              hipStream_t stream) {
  const float* F = (const float*)d_in[0];
  const int*   y = (const int*)d_in[1];
  float* out = (float*)d_out;

  uint8_t* Fb = (uint8_t*)d_ws;                               // 4 MB fp8
  float*  sq = (float*)((char*)d_ws + (size_t)NROWS * DDIM);
  float*  rn = sq + NROWS;
  float*  partials = rn + NROWS;

  prep_kernel<<<NROWS / 4, 256, 0, stream>>>(F, Fb, sq, rn);
  gram_kernel<<<GBLK, 512, 0, stream>>>(Fb, sq, rn, y, partials);
  reduce_kernel<<<1, 256, 0, stream>>>(partials, out);
}